// Round 4
// baseline (293.731 us; speedup 1.0000x reference)
//
#include <hip/hip_runtime.h>

// TinyMLP (2 -> 32 -> 32 -> 1, sigmoid) analytic input-gradient, fused, MFMA-based.
// TRANSPOSED dataflow (batch on lane&15 throughout; weights are MFMA A-operands):
//   MFMA#0 (x2): -log2e*Z1^T = aW1 @ Y^T      (y hi/lo bf16 split, b1 in K-slots 6,7)
//   MFMA#1 (x2): -log2e*Z2^T = bW2s @ H1^T    (acc init = -log2e*b2, exp2-ready)
//   MFMA#2 (x2): dH1^T = (W2*W3) @ dZ2^T      (W3 folded into weights at init)
//   MFMA#3 (x1): dY^T  = W1 @ dZ1^T           (g1,g2 land in accY[0],accY[1], lanes 0-15)
//
// R3 (resubmit after infra failure): R2's stage-batched tile pair (A = idx, B = idx+16)
// + DISTANCE-1 PREFETCH of the y-loads. R1/R2 evidence: VALUBusy pinned at ~54%
// regardless of ILP (pairing) or TLP (8 vs 6 blocks/CU) -> waves stall in phase on the
// y-load at the head of each tile chain (FETCH ~36MB/dispatch = substantial L3 misses,
// ~900cy). The trailing wave_barrier pinned those loads inside the iteration. Now:
// next pair's y issues at the top of the body (use is a full body + 4 barriers away,
// ~1200cy cover); x moves to the top too (used only in stage4). Grid 2048 / 8
// blocks/CU for full TLP.
//
// Layouts (16x16x32 bf16, verified m89/m91/m120):
//   A-frag: lane holds A[m=lane&15][k=(lane>>4)*8+j]
//   B-frag: lane holds B[k=(lane>>4)*8+j][n=lane&15]
//   C/D:    lane holds D[row=(lane>>4)*4+r][col=lane&15]

#define H 32
#define NLOG2E (-1.4426950408889634f)

typedef __attribute__((ext_vector_type(8))) short bf16x8;
typedef __attribute__((ext_vector_type(4))) float f32x4;
typedef __attribute__((ext_vector_type(2))) float f32x2;
typedef __attribute__((ext_vector_type(2))) __bf16 bfx2;

#define MFMA16 __builtin_amdgcn_mfma_f32_16x16x32_bf16

__device__ __forceinline__ int cvt_pk_bf16(float a, float b) {
    f32x2 f; f[0] = a; f[1] = b;
    bfx2 r = __builtin_convertvector(f, bfx2);   // v_cvt_pk_bf16_f32 (RNE)
    return __builtin_bit_cast(int, r);
}
__device__ __forceinline__ unsigned f2bf(float f) {          // RNE bf16 bits
    return (unsigned)cvt_pk_bf16(f, 0.f) & 0xFFFFu;
}
__device__ __forceinline__ float bf2f(unsigned s) {          // bf16 bits -> float
    unsigned u = s << 16; return __builtin_bit_cast(float, u);
}
__device__ __forceinline__ float pklo(int p) {               // low bf16 of packed pair
    unsigned u = (unsigned)p << 16; return __builtin_bit_cast(float, u);
}
__device__ __forceinline__ float pkhi(int p) {               // high bf16 of packed pair
    unsigned u = (unsigned)p & 0xFFFF0000u; return __builtin_bit_cast(float, u);
}

// Batched reciprocal: one v_rcp_f32 for four positive values (a_i = 1+e, e in (0,256]:
// product <= ~3.3e8, no overflow; error ~few ulp, far below bf16 rounding).
__device__ __forceinline__ f32x4 rcp4(const f32x4 a) {
    float m01 = a[0] * a[1], m23 = a[2] * a[3];
    float r   = __builtin_amdgcn_rcpf(m01 * m23);
    float r01 = r * m23, r23 = r * m01;
    f32x4 s; s[0] = a[1] * r01; s[1] = a[0] * r01; s[2] = a[3] * r23; s[3] = a[2] * r23;
    return s;
}

__global__ __launch_bounds__(256, 8) void tinymlp_mfma_kernel(
    const float* __restrict__ x1, const float* __restrict__ x2,
    const float* __restrict__ y1, const float* __restrict__ y2,
    const float* __restrict__ W1, const float* __restrict__ b1,
    const float* __restrict__ W2, const float* __restrict__ b2,
    const float* __restrict__ W3,
    float4* __restrict__ out, int ntiles)
{
    // 4 waves x 2048 shorts: per wave, tile A {R0 @0, R1 @512}, tile B {R0 @1024, R1 @1536}
    __shared__ unsigned short lds0[8192];

    const int tid  = threadIdx.x;
    const int w    = tid >> 6;
    const int lane = tid & 63;
    const int m    = lane & 15;
    const int q    = lane >> 4;
    const int kb   = q * 8;

    // ---- wave-invariant weight fragments (all as MFMA A-operands) ----
    bf16x8 bW2s_0, bW2s_1, bW2T3_0, bW2T3_1, bW1r;
    #pragma unroll
    for (int j = 0; j < 8; ++j) {
        // A[h2][h1] = -log2e*W2[h1][h2]  (forward, exp2-ready scale folded)
        bW2s_0[j] = (short)f2bf(NLOG2E * W2[(kb + j) * H + m]);
        bW2s_1[j] = (short)f2bf(NLOG2E * W2[(kb + j) * H + m + 16]);
        // A[h1][h2] = W2[h1][h2]*W3[h2]  (backward, W3 pre-folded)
        const float w3 = W3[kb + j];
        bW2T3_0[j] = (short)f2bf(W2[m * H + kb + j] * w3);
        bW2T3_1[j] = (short)f2bf(W2[(m + 16) * H + kb + j] * w3);
        // A[c][h1] = W1[c][h1], rows >=2 are zero (dY^T)
        bW1r[j] = (m < 2) ? (short)f2bf(W1[m * H + kb + j]) : (short)0;
    }

    // layer-1 A-frags: hi/lo bf16 split of (-log2e*W1), b1 exact via K-slots 6,7.
    // K slots: 0,1 = whi (x yhi); 2,3 = wlo (x yhi); 4,5 = whi (x ylo); 6,7 = b1 hi/lo (x 1).
    union { int i[4]; bf16x8 v; } uW1lo, uW1hi;
    uW1lo.i[0] = uW1lo.i[1] = uW1lo.i[2] = uW1lo.i[3] = 0;
    uW1hi.i[0] = uW1hi.i[1] = uW1hi.i[2] = uW1hi.i[3] = 0;
    if (q == 0) {
        #pragma unroll
        for (int half = 0; half < 2; ++half) {
            const int h = m + 16 * half;
            const float wa = NLOG2E * W1[h];
            const float wb = NLOG2E * W1[H + h];
            const float bv = NLOG2E * b1[h];
            const unsigned ah = f2bf(wa), bh = f2bf(wb);
            const unsigned al = f2bf(wa - bf2f(ah)), bl = f2bf(wb - bf2f(bh));
            const unsigned ch = f2bf(bv);
            const unsigned cl = f2bf(bv - bf2f(ch));
            int i0 = (int)(ah | (bh << 16));
            int i1 = (int)(al | (bl << 16));
            int i3 = (int)(ch | (cl << 16));
            if (half == 0) { uW1lo.i[0] = i0; uW1lo.i[1] = i1; uW1lo.i[2] = i0; uW1lo.i[3] = i3; }
            else           { uW1hi.i[0] = i0; uW1hi.i[1] = i1; uW1hi.i[2] = i0; uW1hi.i[3] = i3; }
        }
    }

    // acc init for MFMA#1: -log2e*b2 at rows h2 = 4q+r (+16)
    f32x4 b2C0, b2C1;
    {
        const float4 t0 = ((const float4*)b2)[q];
        const float4 t1 = ((const float4*)b2)[q + 4];
        b2C0[0] = NLOG2E * t0.x; b2C0[1] = NLOG2E * t0.y; b2C0[2] = NLOG2E * t0.z; b2C0[3] = NLOG2E * t0.w;
        b2C1[0] = NLOG2E * t1.x; b2C1[1] = NLOG2E * t1.y; b2C1[2] = NLOG2E * t1.z; b2C1[3] = NLOG2E * t1.w;
    }

    // ---- LDS scatter addressing: value (batch=b, k) at short index
    //      (k>>3)*128 + b*8 + (k&7).  Writer lane (q,m): k = 4q+r (lo half) and 16+4q+r
    //      (hi half), one ds_write_b64 each; reader lane reads 8 contiguous shorts.
    const int woff = (q >> 1) * 128 + m * 8 + (q & 1) * 4;
    unsigned short*       wpA = &lds0[w * 2048 + woff];
    unsigned short*       wpB = &lds0[w * 2048 + 1024 + woff];
    const unsigned short* rpA = &lds0[w * 2048 + lane * 8];
    const unsigned short* rpB = &lds0[w * 2048 + 1024 + lane * 8];

    const f32x4 zf = {0.f, 0.f, 0.f, 0.f};

    // ---- per-tile stages (inlined; two independent instances per barrier region) ----
    auto stage1 = [&](float y1v, float y2v, unsigned short* wp, int* P) {
        const int pkHI = cvt_pk_bf16(y1v, y2v);
        const float l1 = y1v - pklo(pkHI);
        const float l2 = y2v - pkhi(pkHI);
        const int pkLO = cvt_pk_bf16(l1, l2);
        union { int i[4]; bf16x8 v; } uY;
        uY.i[0] = pkHI; uY.i[1] = pkHI; uY.i[2] = pkLO; uY.i[3] = 0x3F803F80;  // (1.0,1.0)
        f32x4 zL = MFMA16(uW1lo.v, uY.v, zf, 0, 0, 0);
        f32x4 zH = MFMA16(uW1hi.v, uY.v, zf, 0, 0, 0);
        f32x4 aL, aH;
        #pragma unroll
        for (int r = 0; r < 4; ++r) {
            aL[r] = __builtin_amdgcn_exp2f(zL[r]);
            aH[r] = __builtin_amdgcn_exp2f(zH[r]);
        }
        aL += 1.0f; aH += 1.0f;
        const f32x4 sL = rcp4(aL);
        const f32x4 sH = rcp4(aH);
        P[0] = cvt_pk_bf16(sL[0], sL[1]);
        P[1] = cvt_pk_bf16(sL[2], sL[3]);
        P[2] = cvt_pk_bf16(sH[0], sH[1]);
        P[3] = cvt_pk_bf16(sH[2], sH[3]);
        int2 wv0; wv0.x = P[0]; wv0.y = P[1];
        int2 wv1; wv1.x = P[2]; wv1.y = P[3];
        *(int2*)wp         = wv0;
        *(int2*)(wp + 256) = wv1;
    };

    auto stage2 = [&](const unsigned short* rp, unsigned short* wp) {
        const bf16x8 uaH = *(const bf16x8*)rp;
        f32x4 zzL = MFMA16(bW2s_0, uaH, b2C0, 0, 0, 0);
        f32x4 zzH = MFMA16(bW2s_1, uaH, b2C1, 0, 0, 0);
        f32x4 cL, cH;
        #pragma unroll
        for (int r = 0; r < 4; ++r) {
            cL[r] = __builtin_amdgcn_exp2f(zzL[r]);
            cH[r] = __builtin_amdgcn_exp2f(zzH[r]);
        }
        cL += 1.0f; cH += 1.0f;
        const f32x4 s2L = rcp4(cL);
        const f32x4 s2H = rcp4(cH);
        f32x2 d0; d0[0] = s2L[0]; d0[1] = s2L[1]; d0 = __builtin_elementwise_fma(-d0, d0, d0);
        f32x2 d1; d1[0] = s2L[2]; d1[1] = s2L[3]; d1 = __builtin_elementwise_fma(-d1, d1, d1);
        f32x2 d2; d2[0] = s2H[0]; d2[1] = s2H[1]; d2 = __builtin_elementwise_fma(-d2, d2, d2);
        f32x2 d3; d3[0] = s2H[2]; d3[1] = s2H[3]; d3 = __builtin_elementwise_fma(-d3, d3, d3);
        int2 qv0; qv0.x = cvt_pk_bf16(d0[0], d0[1]); qv0.y = cvt_pk_bf16(d1[0], d1[1]);
        int2 qv1; qv1.x = cvt_pk_bf16(d2[0], d2[1]); qv1.y = cvt_pk_bf16(d3[0], d3[1]);
        *(int2*)(wp + 512) = qv0;
        *(int2*)(wp + 768) = qv1;
    };

    auto stage3 = [&](const unsigned short* rp, unsigned short* wp, const int* P) {
        const bf16x8 aD = *(const bf16x8*)(rp + 512);
        f32x4 dLo = MFMA16(bW2T3_0, aD, zf, 0, 0, 0);
        f32x4 dHi = MFMA16(bW2T3_1, aD, zf, 0, 0, 0);
        f32x2 sv, gg, h0;
        sv[0] = pklo(P[0]); sv[1] = pkhi(P[0]);
        h0 = __builtin_elementwise_fma(-sv, sv, sv);
        gg[0] = dLo[0]; gg[1] = dLo[1]; gg *= h0;
        const int G0 = cvt_pk_bf16(gg[0], gg[1]);
        sv[0] = pklo(P[1]); sv[1] = pkhi(P[1]);
        h0 = __builtin_elementwise_fma(-sv, sv, sv);
        gg[0] = dLo[2]; gg[1] = dLo[3]; gg *= h0;
        const int G1 = cvt_pk_bf16(gg[0], gg[1]);
        sv[0] = pklo(P[2]); sv[1] = pkhi(P[2]);
        h0 = __builtin_elementwise_fma(-sv, sv, sv);
        gg[0] = dHi[0]; gg[1] = dHi[1]; gg *= h0;
        const int G2 = cvt_pk_bf16(gg[0], gg[1]);
        sv[0] = pklo(P[3]); sv[1] = pkhi(P[3]);
        h0 = __builtin_elementwise_fma(-sv, sv, sv);
        gg[0] = dHi[2]; gg[1] = dHi[3]; gg *= h0;
        const int G3 = cvt_pk_bf16(gg[0], gg[1]);
        int2 gv0; gv0.x = G0; gv0.y = G1;
        int2 gv1; gv1.x = G2; gv1.y = G3;
        *(int2*)wp         = gv0;
        *(int2*)(wp + 256) = gv1;
    };

    auto stage4 = [&](const unsigned short* rp, float xv1, float xv2,
                      float yv1, float yv2, unsigned oidx) {
        const bf16x8 uaG = *(const bf16x8*)rp;
        f32x4 accY = MFMA16(bW1r, uaG, zf, 0, 0, 0);
        if (lane < 16) {
            float4 o;
            o.x = xv1 + accY[0];
            o.y = xv2 + accY[1];
            o.z = yv1;
            o.w = yv2;
            out[oidx] = o;
        }
    };

    const int gpair  = (blockIdx.x * blockDim.x + tid) >> 6;
    const int nwaves = (gridDim.x * blockDim.x) >> 6;
    const int npairs = ntiles >> 1;
    if (gpair >= npairs) return;
    unsigned idx = (unsigned)gpair * 32 + (unsigned)m;   // tile A element; B = idx+16
    const unsigned step = (unsigned)nwaves * 32;

    // prologue: first pair's y values
    float yA1 = y1[idx], yA2 = y2[idx];
    float yB1 = y1[idx + 16], yB2 = y2[idx + 16];

    for (int p = gpair; p < npairs; p += nwaves) {
        // next pair's index (clamped on the last iteration: reload current, harmless)
        const unsigned idxn = (p + nwaves < npairs) ? idx + step : idx;

        // ---- distance-1 prefetch: next pair's y; use is a full body away ----
        const float nyA1 = y1[idxn];
        const float nyA2 = y2[idxn];
        const float nyB1 = y1[idxn + 16];
        const float nyB2 = y2[idxn + 16];
        // current pair's x: used only in stage4 (~3 stages of latency cover)
        float xA1 = 0.f, xA2 = 0.f, xB1 = 0.f, xB2 = 0.f;
        if (lane < 16) {
            xA1 = x1[idx];      xA2 = x2[idx];
            xB1 = x1[idx + 16]; xB2 = x2[idx + 16];
        }

        int PA[4], PB[4];
        stage1(yA1, yA2, wpA, PA);
        stage1(yB1, yB2, wpB, PB);
        __builtin_amdgcn_wave_barrier();

        stage2(rpA, wpA);
        stage2(rpB, wpB);
        __builtin_amdgcn_wave_barrier();

        stage3(rpA, wpA, PA);
        stage3(rpB, wpB, PB);
        __builtin_amdgcn_wave_barrier();

        stage4(rpA, xA1, xA2, yA1, yA2, idx);
        stage4(rpB, xB1, xB2, yB1, yB2, idx + 16);
        __builtin_amdgcn_wave_barrier();   // next iteration's LDS writes stay behind reads

        yA1 = nyA1; yA2 = nyA2; yB1 = nyB1; yB2 = nyB2;
        idx = idxn;
    }
}

extern "C" void kernel_launch(void* const* d_in, const int* in_sizes, int n_in,
                              void* d_out, int out_size, void* d_ws, size_t ws_size,
                              hipStream_t stream) {
    const float* x1 = (const float*)d_in[0];
    const float* x2 = (const float*)d_in[1];
    const float* y1 = (const float*)d_in[2];
    const float* y2 = (const float*)d_in[3];
    const float* W1 = (const float*)d_in[4];
    const float* b1 = (const float*)d_in[5];
    const float* W2 = (const float*)d_in[6];
    const float* b2 = (const float*)d_in[7];
    const float* W3 = (const float*)d_in[8];
    // d_in[9] = b3: drops out of the input-gradient — unused.

    const int n = in_sizes[0];
    const int ntiles = n / 16;       // B = 4194304 -> 262144 tiles (131072 pairs)
    const int block = 256;           // 4 waves
    const int grid = 2048;           // 8 blocks/CU (16 KB LDS x 8 = 128 KB, <=64 VGPR)
    tinymlp_mfma_kernel<<<grid, block, 0, stream>>>(
        x1, x2, y1, y2, W1, b1, W2, b2, W3, (float4*)d_out, ntiles);
}

// Round 5
// 203.935 us; speedup vs baseline: 1.4403x; 1.4403x over previous
//
#include <hip/hip_runtime.h>

// TinyMLP (2 -> 32 -> 32 -> 1, sigmoid) analytic input-gradient, fused, MFMA-based.
// R5: 32-wide batch tiles on 32x32x16 MFMAs (was 16-wide on 16x16x32).
// TRANSPOSED dataflow: batch on the 32-wide column dim (lane&31) throughout;
// weights are wave-invariant A-operands; q5 = lane>>5 selects the h/k half.
//   MFMA z1  (x1): -log2e*Z1^T = A_z1 @ Y^T    (y hi/lo bf16 split, b1 in K-slots 6,7)
//   MFMA z2  (x2): -log2e*Z2^T = W2s @ H1^T    (K=32 chained; acc init = -log2e*b2)
//   MFMA dh1 (x2): dH1^T = (W2*W3) @ dZ2^T     (W3 folded into weights at init)
//   MFMA dy  (x2): dY^T  = W1 @ dZ1^T          (g1,g2 = regs 0,1 of lanes 0-31)
// Rationale (R1/R2/R4 evidence): latency-bound — per-pair chain 6912cy vs 5 resident
// waves x 1226cy issue demand. 32-wide tiles halve the number of serial chains per
// element at the same transcendental count; all LDS pivots become fully contiguous
// (bank conflicts ~0); dh1 C-layout == z1 C-layout so h1' multiply stays in-register.
// NO cross-iteration register prefetch (R4: spill catastrophe, FETCH/WRITE x4-x7).
//
// Layouts (32x32x16 bf16; C verified m74/m101, A/B by analogy with verified 16x16x32):
//   A-frag: lane holds A[row=lane&31][k=(lane>>5)*8+j]
//   B-frag: lane holds B[k=(lane>>5)*8+j][n=lane&31]
//   C/D:    lane holds D[row=(reg&3)+8*(reg>>2)+4*(lane>>5)][col=lane&31]
//
// LDS pivot (per wave, two 1024-short regions R0/R1): value (batch b, k) at short
// index (k>>3)*256 + b*8 + (k&7). Writer lane (q5,b): reg pair (4t+e) has k =
// 8t+4q5+e -> one int2 at t*256 + b*8 + 4q5 per t (4x ds_write_b64, contiguous
// 1KB/wave). Reader lane (q5,n): 8 shorts at (blk)*256 + n*8 (ds_read_b128,
// contiguous 1KB/wave). Both conflict-free.

#define H 32
#define NLOG2E (-1.4426950408889634f)

typedef __attribute__((ext_vector_type(8))) short bf16x8;
typedef __attribute__((ext_vector_type(16))) float f32x16;
typedef __attribute__((ext_vector_type(4))) float f32x4;
typedef __attribute__((ext_vector_type(2))) float f32x2;
typedef __attribute__((ext_vector_type(2))) __bf16 bfx2;

#define MFMA32 __builtin_amdgcn_mfma_f32_32x32x16_bf16

__device__ __forceinline__ int cvt_pk_bf16(float a, float b) {
    f32x2 f; f[0] = a; f[1] = b;
    bfx2 r = __builtin_convertvector(f, bfx2);   // v_cvt_pk_bf16_f32 (RNE)
    return __builtin_bit_cast(int, r);
}
__device__ __forceinline__ float pklo(int p) {               // low bf16 of packed pair
    unsigned u = (unsigned)p << 16; return __builtin_bit_cast(float, u);
}
__device__ __forceinline__ float pkhi(int p) {               // high bf16 of packed pair
    unsigned u = (unsigned)p & 0xFFFF0000u; return __builtin_bit_cast(float, u);
}

// Batched reciprocal: one v_rcp_f32 for four positive values (a_i = 1+e, e <= ~2^8:
// product <= ~3.4e8, no overflow; error ~few ulp, far below bf16 rounding).
__device__ __forceinline__ f32x4 rcp4(const f32x4 a) {
    float m01 = a[0] * a[1], m23 = a[2] * a[3];
    float r   = __builtin_amdgcn_rcpf(m01 * m23);
    float r01 = r * m23, r23 = r * m01;
    f32x4 s; s[0] = a[1] * r01; s[1] = a[0] * r01; s[2] = a[3] * r23; s[3] = a[2] * r23;
    return s;
}

__global__ __launch_bounds__(256, 6) void tinymlp_mfma_kernel(
    const float* __restrict__ x1, const float* __restrict__ x2,
    const float* __restrict__ y1, const float* __restrict__ y2,
    const float* __restrict__ W1, const float* __restrict__ b1,
    const float* __restrict__ W2, const float* __restrict__ b2,
    const float* __restrict__ W3,
    float4* __restrict__ out, int ntiles)
{
    // 4 waves x 2048 shorts: per wave R0 @0 (h1, later dz1), R1 @1024 (dz2)
    __shared__ unsigned short lds0[8192];

    const int tid  = threadIdx.x;
    const int w    = tid >> 6;
    const int lane = tid & 63;
    const int n    = lane & 31;   // batch column (and weight row for A-frags)
    const int q5   = lane >> 5;   // k-half / h-half selector

    union U4 { int i[4]; bf16x8 v; };
    U4 A_z1, A_z2a, A_z2b, A_dh1a, A_dh1b, A_dya, A_dyb;

    #pragma unroll
    for (int t = 0; t < 4; ++t) {
        const int j0 = 8 * q5 + 2 * t;
        const int j1 = j0 + 1;
        // z2: A[h2=n][k=h1], forward scale folded
        A_z2a.i[t] = cvt_pk_bf16(NLOG2E * W2[j0 * H + n],        NLOG2E * W2[j1 * H + n]);
        A_z2b.i[t] = cvt_pk_bf16(NLOG2E * W2[(16 + j0) * H + n], NLOG2E * W2[(16 + j1) * H + n]);
        // dh1: A[h1=n][k=h2], W3 pre-folded
        A_dh1a.i[t] = cvt_pk_bf16(W2[n * H + j0] * W3[j0],           W2[n * H + j1] * W3[j1]);
        A_dh1b.i[t] = cvt_pk_bf16(W2[n * H + 16 + j0] * W3[16 + j0], W2[n * H + 16 + j1] * W3[16 + j1]);
        // dy: A[c=n][k=h1], rows >= 2 zero
        A_dya.i[t] = (n < 2) ? cvt_pk_bf16(W1[n * H + j0],      W1[n * H + j1])      : 0;
        A_dyb.i[t] = (n < 2) ? cvt_pk_bf16(W1[n * H + 16 + j0], W1[n * H + 16 + j1]) : 0;
    }

    // z1 A-frag: k-slots (q5==0 half): {whi0,whi1, wlo0,wlo1, whi0,whi1, b1hi,b1lo}
    // pairing with B = {y1hi,y2hi, y1hi,y2hi, y1lo,y2lo, 1,1}; q5==1 half all zero.
    A_z1.i[0] = A_z1.i[1] = A_z1.i[2] = A_z1.i[3] = 0;
    if (q5 == 0) {
        const float wa = NLOG2E * W1[n];
        const float wb = NLOG2E * W1[H + n];
        const float bv = NLOG2E * b1[n];
        const int hi  = cvt_pk_bf16(wa, wb);
        const int lo  = cvt_pk_bf16(wa - pklo(hi), wb - pkhi(hi));
        const int bh  = cvt_pk_bf16(bv, 0.f);
        const int bhl = cvt_pk_bf16(bv, bv - pklo(bh));
        A_z1.i[0] = hi; A_z1.i[1] = lo; A_z1.i[2] = hi; A_z1.i[3] = bhl;
    }

    // acc init for z2: -log2e*b2 at rows h2 = (r&3)+8*(r>>2)+4*q5
    f32x16 b2C;
    #pragma unroll
    for (int t = 0; t < 4; ++t) {
        const float4 bt = *(const float4*)&b2[8 * t + 4 * q5];
        b2C[4 * t + 0] = NLOG2E * bt.x; b2C[4 * t + 1] = NLOG2E * bt.y;
        b2C[4 * t + 2] = NLOG2E * bt.z; b2C[4 * t + 3] = NLOG2E * bt.w;
    }

    f32x16 zf16;
    #pragma unroll
    for (int r = 0; r < 16; ++r) zf16[r] = 0.f;

    unsigned short*       wb = &lds0[w * 2048 + n * 8 + q5 * 4];
    const unsigned short* rb = &lds0[w * 2048 + q5 * 256 + n * 8];

    const int gwave  = (blockIdx.x * blockDim.x + tid) >> 6;
    const int nwaves = (gridDim.x * blockDim.x) >> 6;
    unsigned idx = (unsigned)gwave * 32 + (unsigned)n;   // lanes 0-31 load/store
    const unsigned step = (unsigned)nwaves * 32;

    for (int tt = gwave; tt < ntiles; tt += nwaves) {
        float y1v = 0.f, y2v = 0.f;
        if (lane < 32) { y1v = y1[idx]; y2v = y2[idx]; }

        // ---- B-frag for z1: y hi/lo split; lanes>=32 contribute zero K-slots ----
        U4 uY;
        const int pkHI = cvt_pk_bf16(y1v, y2v);
        const int pkLO = cvt_pk_bf16(y1v - pklo(pkHI), y2v - pkhi(pkHI));
        uY.i[0] = pkHI; uY.i[1] = pkHI; uY.i[2] = pkLO;
        uY.i[3] = (lane < 32) ? 0x3F803F80 : 0;   // (1.0,1.0) bias slots

        // ---- z1^T (scaled): one 32x32x16 MFMA ----
        const f32x16 acc = MFMA32(A_z1.v, uY.v, zf16, 0, 0, 0);

        // ---- sigmoid layer 1: 16 exp2 + 4 rcp; pack s -> P; scatter to R0 ----
        int P[8];
        #pragma unroll
        for (int t = 0; t < 4; ++t) {
            f32x4 e;
            #pragma unroll
            for (int r = 0; r < 4; ++r) e[r] = __builtin_amdgcn_exp2f(acc[4 * t + r]);
            e += 1.0f;
            const f32x4 s = rcp4(e);
            P[2 * t]     = cvt_pk_bf16(s[0], s[1]);
            P[2 * t + 1] = cvt_pk_bf16(s[2], s[3]);
            int2 v; v.x = P[2 * t]; v.y = P[2 * t + 1];
            *(int2*)(wb + t * 256) = v;
        }
        __builtin_amdgcn_wave_barrier();

        // ---- z2^T (scaled, b2 in acc init): K=32 via 2 chained MFMAs ----
        const bf16x8 B1 = *(const bf16x8*)rb;
        const bf16x8 B2 = *(const bf16x8*)(rb + 512);
        f32x16 zz = MFMA32(A_z2a.v, B1, b2C, 0, 0, 0);
        zz = MFMA32(A_z2b.v, B2, zz, 0, 0, 0);

        // ---- dz2 = s2*(1-s2) (W3 folded into dh1 A); pack; scatter to R1 ----
        #pragma unroll
        for (int t = 0; t < 4; ++t) {
            f32x4 e;
            #pragma unroll
            for (int r = 0; r < 4; ++r) e[r] = __builtin_amdgcn_exp2f(zz[4 * t + r]);
            e += 1.0f;
            const f32x4 s = rcp4(e);
            f32x2 sv;
            sv[0] = s[0]; sv[1] = s[1];
            sv = __builtin_elementwise_fma(-sv, sv, sv);
            const int q0 = cvt_pk_bf16(sv[0], sv[1]);
            sv[0] = s[2]; sv[1] = s[3];
            sv = __builtin_elementwise_fma(-sv, sv, sv);
            const int q1 = cvt_pk_bf16(sv[0], sv[1]);
            int2 v; v.x = q0; v.y = q1;
            *(int2*)(wb + 1024 + t * 256) = v;
        }
        __builtin_amdgcn_wave_barrier();

        // x loads here: ~2 stages of latency cover before use in the store
        float xv1 = 0.f, xv2 = 0.f;
        if (lane < 32) { xv1 = x1[idx]; xv2 = x2[idx]; }

        // ---- dH1^T = (W2*W3) @ dZ2^T ----
        const bf16x8 D1 = *(const bf16x8*)(rb + 1024);
        const bf16x8 D2 = *(const bf16x8*)(rb + 1536);
        f32x16 dh = MFMA32(A_dh1a.v, D1, zf16, 0, 0, 0);
        dh = MFMA32(A_dh1b.v, D2, dh, 0, 0, 0);

        // ---- dz1 = dH1 * h1d (same C-layout as z1 -> in-register); scatter to R0 ----
        #pragma unroll
        for (int t = 0; t < 4; ++t) {
            f32x2 sv, gg;
            sv[0] = pklo(P[2 * t]); sv[1] = pkhi(P[2 * t]);
            sv = __builtin_elementwise_fma(-sv, sv, sv);
            gg[0] = dh[4 * t]; gg[1] = dh[4 * t + 1]; gg *= sv;
            const int g0 = cvt_pk_bf16(gg[0], gg[1]);
            sv[0] = pklo(P[2 * t + 1]); sv[1] = pkhi(P[2 * t + 1]);
            sv = __builtin_elementwise_fma(-sv, sv, sv);
            gg[0] = dh[4 * t + 2]; gg[1] = dh[4 * t + 3]; gg *= sv;
            const int g1 = cvt_pk_bf16(gg[0], gg[1]);
            int2 v; v.x = g0; v.y = g1;
            *(int2*)(wb + t * 256) = v;
        }
        __builtin_amdgcn_wave_barrier();

        // ---- dY^T = W1 @ dZ1^T: lanes 0-31 hold g1=reg0, g2=reg1 ----
        const bf16x8 E1 = *(const bf16x8*)rb;
        const bf16x8 E2 = *(const bf16x8*)(rb + 512);
        f32x16 ay = MFMA32(A_dya.v, E1, zf16, 0, 0, 0);
        ay = MFMA32(A_dyb.v, E2, ay, 0, 0, 0);

        if (lane < 32) {
            float4 o;
            o.x = xv1 + ay[0];
            o.y = xv2 + ay[1];
            o.z = y1v;
            o.w = y2v;
            out[idx] = o;
        }
        __builtin_amdgcn_wave_barrier();   // next iter's R0 writes stay behind E-reads

        idx += step;
    }
}

extern "C" void kernel_launch(void* const* d_in, const int* in_sizes, int n_in,
                              void* d_out, int out_size, void* d_ws, size_t ws_size,
                              hipStream_t stream) {
    const float* x1 = (const float*)d_in[0];
    const float* x2 = (const float*)d_in[1];
    const float* y1 = (const float*)d_in[2];
    const float* y2 = (const float*)d_in[3];
    const float* W1 = (const float*)d_in[4];
    const float* b1 = (const float*)d_in[5];
    const float* W2 = (const float*)d_in[6];
    const float* b2 = (const float*)d_in[7];
    const float* W3 = (const float*)d_in[8];
    // d_in[9] = b3: drops out of the input-gradient — unused.

    const int n = in_sizes[0];
    const int ntiles = n / 32;       // B = 4194304 -> 131072 tiles of 32
    const int block = 256;           // 4 waves
    const int grid = 1536;           // 6 blocks/CU resident (16 KB LDS, <=84 VGPR)
    tinymlp_mfma_kernel<<<grid, block, 0, stream>>>(
        x1, x2, y1, y2, W1, b1, W2, b2, W3, (float4*)d_out, ntiles);
}